// Round 2
// baseline (9587.560 us; speedup 1.0000x reference)
//
#include <hip/hip_runtime.h>
#include <math.h>

// ---------------------------------------------------------------------------
// WorldModel (DreamerV2-ish RSSM) forward losses. fp32 correctness baseline.
// R1 change: workspace footprint cut 284MB -> ~93MB (suspected d_ws overflow
// caused the R0 memory-fault abort). FEAT is no longer materialized for all
// 16128 rows; phase A and the head GEMMs are chunked per 7-timestep group.
// ---------------------------------------------------------------------------

namespace {

constexpr int TSTEPS = 63;
constexpr int NB     = 256;
constexpr int NOBS   = 512;
constexpr int NACT   = 32;
constexpr int NROWS  = TSTEPS * NB;   // 16128
constexpr int TGRP   = 7;             // timesteps per group
constexpr int NGRP   = 9;             // 9*7 = 63
constexpr int GROWS  = TGRP * NB;     // 1792 rows per group (28 x 64)

// workspace offsets, in floats (total ~23.3M floats ~= 93 MB)
constexpr size_t OFF_POSTE = 0;                                    // 16128x512
constexpr size_t OFF_SCR   = OFF_POSTE + (size_t)NROWS * 512;      // scratch
constexpr size_t OFF_FEATC = OFF_SCR;                              // 1792x1280
constexpr size_t OFF_DR1C  = OFF_SCR + (size_t)GROWS * 1280;       // 1792x2048
constexpr size_t OFF_E1C   = OFF_SCR;                              // 1792x1024 (phase A alias)
constexpr size_t OFF_EMBC  = OFF_SCR + (size_t)GROWS * 1024;       // 1792x1024
constexpr size_t OFF_WH    = OFF_SCR + (size_t)GROWS * (1280 + 2048); // 1024x4096
constexpr size_t OFF_WIHT  = OFF_WH + (size_t)1024 * 4096;         // 288x3072
constexpr size_t OFF_WDR   = OFF_WIHT + (size_t)288 * 3072;        // 1280x2048
constexpr size_t OFF_BDR   = OFF_WDR + (size_t)1280 * 2048;        // 2048
constexpr size_t OFF_G     = OFF_BDR + 2048;                       // 256x4096
constexpr size_t OFF_H     = OFF_G + (size_t)NB * 4096;            // 256x1024
constexpr size_t OFF_ACC   = OFF_H + (size_t)NB * 1024;            // 16
constexpr size_t OFF_XBUF  = OFF_ACC + 16;                         // 256x288

__global__ void zero_kernel(float* p, int n) {
  int i = blockIdx.x * 256 + threadIdx.x;
  if (i < n) p[i] = 0.f;
}

// W_h columns 0:512 = prior_w, 512:1024 = post_w rows 0:1024
__global__ void build_wh_left(const float* __restrict__ prior_w,
                              const float* __restrict__ post_w,
                              float* __restrict__ wh) {
  int idx = blockIdx.x * 256 + threadIdx.x;  // 1024*1024
  int k = idx >> 10;
  int c = idx & 1023;
  float v = (c < 512) ? prior_w[k * 512 + c] : post_w[k * 512 + (c - 512)];
  wh[(size_t)k * 4096 + c] = v;
}

// out[(c0+c)*ldo + r0+r] = in[(r0+r)*ldi + c0+c]; rows, cols multiples of 32
__global__ void transpose_kernel(const float* __restrict__ in, float* __restrict__ out,
                                 int ldi, int ldo) {
  __shared__ float tile[32][33];
  int r0 = blockIdx.y * 32, c0 = blockIdx.x * 32;
  int tx = threadIdx.x & 31, ty = threadIdx.x >> 5;  // ty 0..7
#pragma unroll
  for (int p = 0; p < 4; ++p) {
    int r = ty + p * 8;
    tile[r][tx] = in[(size_t)(r0 + r) * ldi + c0 + tx];
  }
  __syncthreads();
#pragma unroll
  for (int p = 0; p < 4; ++p) {
    int c = ty + p * 8;
    out[(size_t)(c0 + c) * ldo + r0 + tx] = tile[tx][c];
  }
}

__global__ void build_wdr(const float* __restrict__ dec_w1, const float* __restrict__ rew_w1,
                          const float* __restrict__ dec_b1, const float* __restrict__ rew_b1,
                          float* __restrict__ wdr, float* __restrict__ bdr) {
  int idx = blockIdx.x * 256 + threadIdx.x;  // 1280*2048
  int k = idx >> 11;
  int c = idx & 2047;
  wdr[idx] = (c < 1024) ? dec_w1[k * 1024 + c] : rew_w1[k * 1024 + (c - 1024)];
  if (idx < 2048) bdr[idx] = (idx < 1024) ? dec_b1[idx] : rew_b1[idx - 1024];
}

// ---------------------------------------------------------------------------
// Generic fp32 GEMM: C[M,N] = A[M,K] @ B[K,N] (+bias)(+relu). Tile 64x64, BK=16,
// 256 threads, 4x4 micro-tile. Grid covers M,N in 64-multiples; K multiple of 16.
// ---------------------------------------------------------------------------
template <bool BIAS, bool RELU>
__global__ __launch_bounds__(256) void gemm_kernel(
    const float* __restrict__ A, const float* __restrict__ Bm,
    const float* __restrict__ bias, float* __restrict__ C,
    int K, int lda, int ldb, int ldc) {
  __shared__ float As[16][68];
  __shared__ float Bs[16][64];
  int tid = threadIdx.x;
  int tx = tid & 15, ty = tid >> 4;
  int m0 = blockIdx.y * 64, n0 = blockIdx.x * 64;
  float acc[4][4] = {};
  for (int k0 = 0; k0 < K; k0 += 16) {
    {
      int r = tid >> 2, c4 = (tid & 3) * 4;
      const float4 v = *(const float4*)(A + (size_t)(m0 + r) * lda + k0 + c4);
      As[c4 + 0][r] = v.x; As[c4 + 1][r] = v.y; As[c4 + 2][r] = v.z; As[c4 + 3][r] = v.w;
    }
    {
      int r = tid >> 4, c = (tid & 15) * 4;
      *(float4*)&Bs[r][c] = *(const float4*)(Bm + (size_t)(k0 + r) * ldb + n0 + c);
    }
    __syncthreads();
#pragma unroll
    for (int kk = 0; kk < 16; ++kk) {
      float4 a4 = *(const float4*)&As[kk][ty * 4];
      float4 b4 = *(const float4*)&Bs[kk][tx * 4];
      float a[4] = {a4.x, a4.y, a4.z, a4.w};
      float b[4] = {b4.x, b4.y, b4.z, b4.w};
#pragma unroll
      for (int i = 0; i < 4; ++i)
#pragma unroll
        for (int j = 0; j < 4; ++j) acc[i][j] = fmaf(a[i], b[j], acc[i][j]);
    }
    __syncthreads();
  }
#pragma unroll
  for (int i = 0; i < 4; ++i) {
    size_t row = m0 + ty * 4 + i;
#pragma unroll
    for (int j = 0; j < 4; ++j) {
      int col = n0 + tx * 4 + j;
      float v = acc[i][j];
      if (BIAS) v += bias[col];
      if (RELU) v = fmaxf(v, 0.f);
      C[row * ldc + col] = v;
    }
  }
}

// ---------------------------------------------------------------------------
// Phase B elementwise: latents, z, kl. grid = 256 blocks (batch), 256 thr (sto)
// G layout per row b: [pm(256) pl(256) qm_h(256) ql_h(256) gh(3072)]
// t = global timestep (for eps/actions/poste); tt = local step in group (feat)
// ---------------------------------------------------------------------------
__global__ __launch_bounds__(256) void step_latent_kernel(
    int t, int tt, const float* __restrict__ G, const float* __restrict__ poste,
    const float* __restrict__ prior_b, const float* __restrict__ eps,
    const float* __restrict__ actions, float* __restrict__ xbuf,
    float* __restrict__ featc, float* __restrict__ acc) {
  int b = blockIdx.x;
  int s = threadIdx.x;
  int row = t * NB + b;
  const float* g = G + (size_t)b * 4096;
  float pm = g[s] + prior_b[s];
  float pl = g[256 + s] + prior_b[256 + s];
  float qm = g[512 + s] + poste[(size_t)row * 512 + s];
  float ql = g[768 + s] + poste[(size_t)row * 512 + 256 + s];
  float e = eps[(size_t)row * 256 + s];
  float z = qm + e * expf(ql);
  xbuf[b * 288 + s] = z;
  featc[(size_t)(tt * NB + b) * 1280 + 1024 + s] = z;
  if (s < NACT) xbuf[b * 288 + 256 + s] = actions[(size_t)row * NACT + s];
  float vq = expf(2.f * ql), vp = expf(2.f * pl);
  float dm = qm - pm;
  float klt = pl - ql + (vq + dm * dm) / (vp + 1e-8f) - 1.f;
  __shared__ float red[256];
  red[s] = klt;
  __syncthreads();
  for (int st = 128; st > 0; st >>= 1) {
    if (s < st) red[s] += red[s + st];
    __syncthreads();
  }
  if (s == 0) atomicAdd(&acc[2], 0.5f * red[0]);
}

// ---------------------------------------------------------------------------
// Phase B GRU: GI = xbuf(256x288) @ wihT(288x3072), 3 gate tiles per block;
// epilogue does gate math -> h_next. grid (16,4), 256 thr.
// ---------------------------------------------------------------------------
__global__ __launch_bounds__(256) void step_gru_kernel(
    int t, int tt, const float* __restrict__ xbuf, const float* __restrict__ wihT,
    const float* __restrict__ G, const float* __restrict__ bih,
    const float* __restrict__ bhh, const unsigned char* __restrict__ dones,
    float* __restrict__ H, float* __restrict__ featc) {
  __shared__ float As[16][68];
  __shared__ float Bs[3][16][64];
  int tid = threadIdx.x;
  int tx = tid & 15, ty = tid >> 4;
  int m0 = blockIdx.y * 64, n0 = blockIdx.x * 64;
  float acc[3][4][4] = {};
  for (int k0 = 0; k0 < 288; k0 += 16) {
    {
      int r = tid >> 2, c4 = (tid & 3) * 4;
      const float4 v = *(const float4*)(xbuf + (size_t)(m0 + r) * 288 + k0 + c4);
      As[c4 + 0][r] = v.x; As[c4 + 1][r] = v.y; As[c4 + 2][r] = v.z; As[c4 + 3][r] = v.w;
    }
    {
      int r = tid >> 4, c = (tid & 15) * 4;
#pragma unroll
      for (int gg = 0; gg < 3; ++gg)
        *(float4*)&Bs[gg][r][c] =
            *(const float4*)(wihT + (size_t)(k0 + r) * 3072 + gg * 1024 + n0 + c);
    }
    __syncthreads();
#pragma unroll
    for (int kk = 0; kk < 16; ++kk) {
      float4 a4 = *(const float4*)&As[kk][ty * 4];
      float a[4] = {a4.x, a4.y, a4.z, a4.w};
#pragma unroll
      for (int gg = 0; gg < 3; ++gg) {
        float4 b4 = *(const float4*)&Bs[gg][kk][tx * 4];
        float b[4] = {b4.x, b4.y, b4.z, b4.w};
#pragma unroll
        for (int i = 0; i < 4; ++i)
#pragma unroll
          for (int j = 0; j < 4; ++j) acc[gg][i][j] = fmaf(a[i], b[j], acc[gg][i][j]);
      }
    }
    __syncthreads();
  }
#pragma unroll
  for (int i = 0; i < 4; ++i) {
    int b = m0 + ty * 4 + i;
    int row = t * NB + b;
    float mask = 1.f - (float)dones[row];
    const float* g = G + (size_t)b * 4096;
#pragma unroll
    for (int jj = 0; jj < 4; ++jj) {
      int j = n0 + tx * 4 + jj;
      float ir = acc[0][i][jj] + bih[j];
      float iz = acc[1][i][jj] + bih[1024 + j];
      float in_ = acc[2][i][jj] + bih[2048 + j];
      float hr = g[1024 + j] + bhh[j];
      float hz = g[2048 + j] + bhh[1024 + j];
      float hn = g[3072 + j] + bhh[2048 + j];
      float r = 1.f / (1.f + expf(-(ir + hr)));
      float u = 1.f / (1.f + expf(-(iz + hz)));
      float n = tanhf(in_ + r * hn);
      float hprev = H[b * 1024 + j];
      float hnext = (1.f - u) * n + u * hprev;
      featc[(size_t)(tt * NB + b) * 1280 + j] = hnext;
      H[b * 1024 + j] = hnext * mask;
    }
  }
}

// ---------------------------------------------------------------------------
// Decoder output GEMM with fused recon loss, per group. A=DR1c cols 0:1024
// (lda 2048), B=dec_w2 (1024x512). M=1792,N=512,K=1024. grid (8,28).
// obs_next_g points at the group's first target row.
// ---------------------------------------------------------------------------
__global__ __launch_bounds__(256) void decobs_loss_kernel(
    const float* __restrict__ A, const float* __restrict__ Bm,
    const float* __restrict__ bias, const float* __restrict__ obs_next_g,
    float* __restrict__ acc) {
  __shared__ float As[16][68];
  __shared__ float Bs[16][64];
  int tid = threadIdx.x;
  int tx = tid & 15, ty = tid >> 4;
  int m0 = blockIdx.y * 64, n0 = blockIdx.x * 64;
  float accv[4][4] = {};
  for (int k0 = 0; k0 < 1024; k0 += 16) {
    {
      int r = tid >> 2, c4 = (tid & 3) * 4;
      const float4 v = *(const float4*)(A + (size_t)(m0 + r) * 2048 + k0 + c4);
      As[c4 + 0][r] = v.x; As[c4 + 1][r] = v.y; As[c4 + 2][r] = v.z; As[c4 + 3][r] = v.w;
    }
    {
      int r = tid >> 4, c = (tid & 15) * 4;
      *(float4*)&Bs[r][c] = *(const float4*)(Bm + (size_t)(k0 + r) * 512 + n0 + c);
    }
    __syncthreads();
#pragma unroll
    for (int kk = 0; kk < 16; ++kk) {
      float4 a4 = *(const float4*)&As[kk][ty * 4];
      float4 b4 = *(const float4*)&Bs[kk][tx * 4];
      float a[4] = {a4.x, a4.y, a4.z, a4.w};
      float b[4] = {b4.x, b4.y, b4.z, b4.w};
#pragma unroll
      for (int i = 0; i < 4; ++i)
#pragma unroll
        for (int j = 0; j < 4; ++j) accv[i][j] = fmaf(a[i], b[j], accv[i][j]);
    }
    __syncthreads();
  }
  float local = 0.f;
#pragma unroll
  for (int i = 0; i < 4; ++i) {
    size_t row = m0 + ty * 4 + i;
#pragma unroll
    for (int j = 0; j < 4; ++j) {
      int col = n0 + tx * 4 + j;
      float v = accv[i][j] + bias[col];
      float d = v - obs_next_g[row * 512 + col];
      local += d * d;
    }
  }
  __shared__ float red[256];
  red[tid] = local;
  __syncthreads();
  for (int st = 128; st > 0; st >>= 1) {
    if (tid < st) red[tid] += red[tid + st];
    __syncthreads();
  }
  if (tid == 0) atomicAdd(&acc[0], red[0]);
}

// Reward head matvec + loss, per group. R1 = DR1c + 1024 (lda 2048).
__global__ __launch_bounds__(256) void rew_loss_kernel(
    const float* __restrict__ R1, const float* __restrict__ w2,
    const float* __restrict__ b2, const float* __restrict__ rewards_g,
    float* __restrict__ acc) {
  int wave = threadIdx.x >> 6;
  int lane = threadIdx.x & 63;
  int row = blockIdx.x * 4 + wave;
  const float* rp = R1 + (size_t)row * 2048;
  float s = 0.f;
#pragma unroll
  for (int i = 0; i < 16; ++i) s += rp[lane + 64 * i] * w2[lane + 64 * i];
  for (int off = 32; off > 0; off >>= 1) s += __shfl_down(s, off);
  if (lane == 0) {
    float d = s + b2[0] - rewards_g[row];
    atomicAdd(&acc[1], d * d);
  }
}

__global__ void finalize_kernel(const float* __restrict__ acc, float* __restrict__ out) {
  float recon = acc[0] / ((float)NROWS * 512.f);
  float rew = acc[1] / (float)NROWS;
  float kl = acc[2] / (float)NROWS;
  out[0] = recon + rew + kl;
  out[1] = recon;
  out[2] = rew;
  out[3] = kl;
}

}  // namespace

extern "C" void kernel_launch(void* const* d_in, const int* in_sizes, int n_in,
                              void* d_out, int out_size, void* d_ws, size_t ws_size,
                              hipStream_t stream) {
  const float* obs     = (const float*)d_in[0];
  const float* actions = (const float*)d_in[1];
  const float* rewards = (const float*)d_in[2];
  const unsigned char* dones = (const unsigned char*)d_in[3];
  const float* eps     = (const float*)d_in[4];
  const float* enc_w1  = (const float*)d_in[5];
  const float* enc_b1  = (const float*)d_in[6];
  const float* enc_w2  = (const float*)d_in[7];
  const float* enc_b2  = (const float*)d_in[8];
  const float* gru_wih = (const float*)d_in[9];
  const float* gru_whh = (const float*)d_in[10];
  const float* gru_bih = (const float*)d_in[11];
  const float* gru_bhh = (const float*)d_in[12];
  const float* prior_w = (const float*)d_in[13];
  const float* prior_b = (const float*)d_in[14];
  const float* post_w  = (const float*)d_in[15];
  const float* post_b  = (const float*)d_in[16];
  const float* dec_w1  = (const float*)d_in[17];
  const float* dec_b1  = (const float*)d_in[18];
  const float* dec_w2  = (const float*)d_in[19];
  const float* dec_b2  = (const float*)d_in[20];
  const float* rew_w1  = (const float*)d_in[21];
  const float* rew_b1  = (const float*)d_in[22];
  const float* rew_w2  = (const float*)d_in[23];
  const float* rew_b2  = (const float*)d_in[24];
  float* out = (float*)d_out;
  float* ws = (float*)d_ws;

  float* POSTE = ws + OFF_POSTE;
  float* FEATC = ws + OFF_FEATC;
  float* DR1C  = ws + OFF_DR1C;
  float* E1C   = ws + OFF_E1C;
  float* EMBC  = ws + OFF_EMBC;
  float* WH    = ws + OFF_WH;
  float* WIHT  = ws + OFF_WIHT;
  float* WDR   = ws + OFF_WDR;
  float* BDR   = ws + OFF_BDR;
  float* G     = ws + OFF_G;
  float* H     = ws + OFF_H;
  float* ACC   = ws + OFF_ACC;
  float* XBUF  = ws + OFF_XBUF;

  // Phase 0: zero h0 + loss accumulators (adjacent); build fused weights
  zero_kernel<<<(NB * 1024 + 16 + 255) / 256, 256, 0, stream>>>(H, NB * 1024 + 16);
  build_wh_left<<<4096, 256, 0, stream>>>(prior_w, post_w, WH);
  // whh (3072x1024) -> WH cols 1024:4096 (= whh^T)
  transpose_kernel<<<dim3(1024 / 32, 3072 / 32), 256, 0, stream>>>(gru_whh, WH + 1024, 1024, 4096);
  // wih (3072x288) -> WIHT (288x3072)
  transpose_kernel<<<dim3(288 / 32, 3072 / 32), 256, 0, stream>>>(gru_wih, WIHT, 288, 3072);
  build_wdr<<<(1280 * 2048) / 256, 256, 0, stream>>>(dec_w1, rew_w1, dec_b1, rew_b1, WDR, BDR);

  // Phase A: encoder + posterior-from-emb, chunked (9 groups x 1792 rows)
  for (int g = 0; g < NGRP; ++g) {
    const float* obs_g = obs + (size_t)g * GROWS * 512;
    gemm_kernel<true, true><<<dim3(16, GROWS / 64), 256, 0, stream>>>(
        obs_g, enc_w1, enc_b1, E1C, 512, 512, 1024, 1024);
    gemm_kernel<true, true><<<dim3(16, GROWS / 64), 256, 0, stream>>>(
        E1C, enc_w2, enc_b2, EMBC, 1024, 1024, 1024, 1024);
    gemm_kernel<true, false><<<dim3(8, GROWS / 64), 256, 0, stream>>>(
        EMBC, post_w + (size_t)1024 * 512, post_b, POSTE + (size_t)g * GROWS * 512,
        1024, 1024, 512, 512);
  }

  // Phase B (sequential steps) interleaved with per-group head losses
  for (int g = 0; g < NGRP; ++g) {
    for (int tt = 0; tt < TGRP; ++tt) {
      int t = g * TGRP + tt;
      gemm_kernel<false, false><<<dim3(64, 4), 256, 0, stream>>>(
          H, WH, nullptr, G, 1024, 1024, 4096, 4096);
      step_latent_kernel<<<NB, 256, 0, stream>>>(t, tt, G, POSTE, prior_b, eps,
                                                 actions, XBUF, FEATC, ACC);
      step_gru_kernel<<<dim3(16, 4), 256, 0, stream>>>(t, tt, XBUF, WIHT, G, gru_bih,
                                                       gru_bhh, dones, H, FEATC);
    }
    // heads for this group's 1792 feat rows
    gemm_kernel<true, true><<<dim3(32, GROWS / 64), 256, 0, stream>>>(
        FEATC, WDR, BDR, DR1C, 1280, 1280, 2048, 2048);
    decobs_loss_kernel<<<dim3(8, GROWS / 64), 256, 0, stream>>>(
        DR1C, dec_w2, dec_b2, obs + ((size_t)g * TGRP + 1) * NB * NOBS, ACC);
    rew_loss_kernel<<<GROWS / 4, 256, 0, stream>>>(
        DR1C + 1024, rew_w2, rew_b2, rewards + (size_t)g * TGRP * NB, ACC);
  }

  finalize_kernel<<<1, 1, 0, stream>>>(ACC, out);
}

// Round 4
// 3579.358 us; speedup vs baseline: 2.6786x; 2.6786x over previous
//
#include <hip/hip_runtime.h>
#include <math.h>

// ---------------------------------------------------------------------------
// WorldModel RSSM forward losses — R2: all GEMMs moved to bf16 MFMA
// (v_mfma_f32_16x16x32_bf16), weights prebuilt as bf16 B^T [N][K], activations
// bf16, accumulation + gate/KL/loss math fp32. 64x64 tile, 4 waves, BK=32.
// R3: fix missing rew_b1 declaration (compile error).
// ---------------------------------------------------------------------------

namespace {

typedef unsigned short ushort;
typedef __attribute__((ext_vector_type(8))) short short8;   // 8 bf16 in 4 VGPRs
typedef __attribute__((ext_vector_type(4))) float f32x4;

constexpr int TSTEPS = 63;
constexpr int NB     = 256;
constexpr int NACT   = 32;
constexpr int NROWS  = TSTEPS * NB;   // 16128
constexpr int TGRP   = 7;
constexpr int NGRP   = 9;
constexpr int GROWS  = TGRP * NB;     // 1792 = 28*64

// ---- workspace layout (floats) --------------------------------------------
constexpr size_t OFF_POSTE = 0;                                     // f32 16128x512
constexpr size_t OFF_OBSB  = OFF_POSTE + (size_t)NROWS * 512;       // u16 1792x512
constexpr size_t OFF_E1C   = OFF_OBSB + (size_t)GROWS * 512 / 2;    // u16 1792x1024
constexpr size_t OFF_EMBC  = OFF_E1C + (size_t)GROWS * 1024 / 2;    // u16 1792x1024
constexpr size_t OFF_FEATC = OFF_EMBC + (size_t)GROWS * 1024 / 2;   // u16 1792x1280
constexpr size_t OFF_DR1C  = OFF_FEATC + (size_t)GROWS * 1280 / 2;  // u16 1792x2048
constexpr size_t OFF_WHT   = OFF_DR1C + (size_t)GROWS * 2048 / 2;   // u16 4096x1024
constexpr size_t OFF_WIHT  = OFF_WHT + (size_t)4096 * 1024 / 2;     // u16 3072x288
constexpr size_t OFF_WDRT  = OFF_WIHT + (size_t)3072 * 288 / 2;     // u16 2048x1280
constexpr size_t OFF_E1T   = OFF_WDRT + (size_t)2048 * 1280 / 2;    // u16 1024x512
constexpr size_t OFF_E2T   = OFF_E1T + (size_t)1024 * 512 / 2;      // u16 1024x1024
constexpr size_t OFF_PET   = OFF_E2T + (size_t)1024 * 1024 / 2;     // u16 512x1024
constexpr size_t OFF_DW2T  = OFF_PET + (size_t)512 * 1024 / 2;      // u16 512x1024
constexpr size_t OFF_BDR   = OFF_DW2T + (size_t)512 * 1024 / 2;     // f32 2048
constexpr size_t OFF_G     = OFF_BDR + 2048;                        // f32 256x4096
constexpr size_t OFF_H     = OFF_G + (size_t)NB * 4096;             // f32 256x1024
constexpr size_t OFF_HB    = OFF_H + (size_t)NB * 1024;             // u16 256x1024
constexpr size_t OFF_ACC   = OFF_HB + (size_t)NB * 1024 / 2;        // f32 16
constexpr size_t OFF_XBUF  = OFF_ACC + 16;                          // u16 256x288
// total ~ 20.2M floats ~= 81 MB

__device__ __forceinline__ ushort f2bf(float f) {
  unsigned int u = __float_as_uint(f);
  unsigned int r = (u + 0x7fffu + ((u >> 16) & 1u)) >> 16;
  return (ushort)r;
}
__device__ __forceinline__ float bf2f(ushort u) {
  return __uint_as_float((unsigned int)u << 16);
}

__global__ void zero_kernel(float* p, int n) {
  int i = blockIdx.x * 256 + threadIdx.x;
  if (i < n) p[i] = 0.f;
}

__global__ void f2bf_kernel(const float* __restrict__ in, ushort* __restrict__ out, int n) {
  int i = blockIdx.x * 256 + threadIdx.x;
  if (i < n) out[i] = f2bf(in[i]);
}

// WHT[n][k], n<512: prior_w[k][n]; n<1024: post_w[k][n-512]; else whh[n-1024][k]
__global__ void build_wht(const float* __restrict__ prior_w, const float* __restrict__ post_w,
                          const float* __restrict__ whh, ushort* __restrict__ out) {
  int idx = blockIdx.x * 256 + threadIdx.x;  // 4096*1024
  int n = idx >> 10, k = idx & 1023;
  float v = (n < 512) ? prior_w[k * 512 + n]
          : (n < 1024) ? post_w[k * 512 + (n - 512)]
                       : whh[(size_t)(n - 1024) * 1024 + k];
  out[idx] = f2bf(v);
}

// out[c*ldo + r] = bf16(in[r*ldi + c]); grid (C/32, R/32)
__global__ void trans_conv(const float* __restrict__ in, ushort* __restrict__ out,
                           int ldi, int ldo) {
  __shared__ float tile[32][33];
  int r0 = blockIdx.y * 32, c0 = blockIdx.x * 32;
  int tx = threadIdx.x & 31, ty = threadIdx.x >> 5;
#pragma unroll
  for (int p = 0; p < 4; ++p)
    tile[ty + p * 8][tx] = in[(size_t)(r0 + ty + p * 8) * ldi + c0 + tx];
  __syncthreads();
#pragma unroll
  for (int p = 0; p < 4; ++p)
    out[(size_t)(c0 + ty + p * 8) * ldo + r0 + tx] = f2bf(tile[tx][ty + p * 8]);
}

__global__ void build_bdr(const float* __restrict__ dec_b1, const float* __restrict__ rew_b1,
                          float* __restrict__ bdr) {
  int i = blockIdx.x * 256 + threadIdx.x;  // 2048
  bdr[i] = (i < 1024) ? dec_b1[i] : rew_b1[i - 1024];
}

// ---------------------------------------------------------------------------
// bf16 MFMA GEMM: C[M,N] = A[M,K] @ B[K,N]; A bf16 [M][K], BT bf16 [N][K].
// 64x64 tile / block (4 waves, each 16 rows x 64 cols), BK=32.
// EPI: 0 = store f32; 1 = +bias, relu, store bf16; 2 = +bias, store f32.
// ---------------------------------------------------------------------------
template <int EPI>
__global__ __launch_bounds__(256) void gemm_bf16(
    const ushort* __restrict__ A, const ushort* __restrict__ BT,
    const float* __restrict__ bias, void* __restrict__ Cv,
    int K, int lda, int ldb, int ldc) {
  __shared__ __align__(16) ushort As[64 * 32];
  __shared__ __align__(16) ushort Bs[64 * 32];
  int tid = threadIdx.x;
  int wave = tid >> 6, lane = tid & 63;
  int quad = lane >> 4, l15 = lane & 15;
  int m0 = blockIdx.y * 64, n0 = blockIdx.x * 64;
  int sr = tid >> 2, sc = (tid & 3) * 8;
  f32x4 acc[4] = {};
  for (int k0 = 0; k0 < K; k0 += 32) {
    *(int4*)&As[sr * 32 + sc] = *(const int4*)(A + (size_t)(m0 + sr) * lda + k0 + sc);
    *(int4*)&Bs[sr * 32 + sc] = *(const int4*)(BT + (size_t)(n0 + sr) * ldb + k0 + sc);
    __syncthreads();
    short8 a = *(const short8*)&As[(wave * 16 + l15) * 32 + quad * 8];
#pragma unroll
    for (int c = 0; c < 4; ++c) {
      short8 b = *(const short8*)&Bs[(c * 16 + l15) * 32 + quad * 8];
      acc[c] = __builtin_amdgcn_mfma_f32_16x16x32_bf16(a, b, acc[c], 0, 0, 0);
    }
    __syncthreads();
  }
#pragma unroll
  for (int c = 0; c < 4; ++c) {
#pragma unroll
    for (int r = 0; r < 4; ++r) {
      size_t row = m0 + wave * 16 + quad * 4 + r;
      int col = n0 + c * 16 + l15;
      float v = acc[c][r];
      if (EPI >= 1) v += bias[col];
      if (EPI == 1) v = fmaxf(v, 0.f);
      if (EPI == 1) ((ushort*)Cv)[row * ldc + col] = f2bf(v);
      else ((float*)Cv)[row * ldc + col] = v;
    }
  }
}

// ---------------------------------------------------------------------------
// Latent/KL elementwise. grid 256 (batch), 256 thr (sto). G row layout:
// [pm(256) pl(256) qm_h(256) ql_h(256) hr(1024) hz(1024) hn(1024)]
// ---------------------------------------------------------------------------
__global__ __launch_bounds__(256) void step_latent_kernel(
    int t, int tt, const float* __restrict__ G, const float* __restrict__ poste,
    const float* __restrict__ prior_b, const float* __restrict__ eps,
    const float* __restrict__ actions, ushort* __restrict__ xbuf,
    ushort* __restrict__ featc, float* __restrict__ acc) {
  int b = blockIdx.x;
  int s = threadIdx.x;
  int row = t * NB + b;
  const float* g = G + (size_t)b * 4096;
  float pm = g[s] + prior_b[s];
  float pl = g[256 + s] + prior_b[256 + s];
  float qm = g[512 + s] + poste[(size_t)row * 512 + s];
  float ql = g[768 + s] + poste[(size_t)row * 512 + 256 + s];
  float e = eps[(size_t)row * 256 + s];
  float z = qm + e * expf(ql);
  xbuf[b * 288 + s] = f2bf(z);
  featc[(size_t)(tt * NB + b) * 1280 + 1024 + s] = f2bf(z);
  if (s < NACT) xbuf[b * 288 + 256 + s] = f2bf(actions[(size_t)row * NACT + s]);
  float vq = expf(2.f * ql), vp = expf(2.f * pl);
  float dm = qm - pm;
  float klt = pl - ql + (vq + dm * dm) / (vp + 1e-8f) - 1.f;
  __shared__ float red[256];
  red[s] = klt;
  __syncthreads();
  for (int st = 128; st > 0; st >>= 1) {
    if (s < st) red[s] += red[s + st];
    __syncthreads();
  }
  if (s == 0) atomicAdd(&acc[2], 0.5f * red[0]);
}

// ---------------------------------------------------------------------------
// GRU step: GI = xbuf(256x288) @ wih^T — 3 gates at once, fused gate epilogue.
// grid (16, 4): 64 gate-cols x 64 batch-rows per block. WIHT = gru_wih bf16
// [3072][288] (already B^T form).
// ---------------------------------------------------------------------------
__global__ __launch_bounds__(256) void gru_step_kernel(
    int t, int tt, const ushort* __restrict__ xbuf, const ushort* __restrict__ wiht,
    const float* __restrict__ G, const float* __restrict__ bih,
    const float* __restrict__ bhh, const unsigned char* __restrict__ dones,
    float* __restrict__ H, ushort* __restrict__ HB, ushort* __restrict__ featc) {
  __shared__ __align__(16) ushort As[64 * 32];
  __shared__ __align__(16) ushort Bs[3][64 * 32];
  int tid = threadIdx.x;
  int wave = tid >> 6, lane = tid & 63;
  int quad = lane >> 4, l15 = lane & 15;
  int m0 = blockIdx.y * 64, n0 = blockIdx.x * 64;
  int sr = tid >> 2, sc = (tid & 3) * 8;
  f32x4 accv[3][4] = {};
  for (int k0 = 0; k0 < 288; k0 += 32) {
    *(int4*)&As[sr * 32 + sc] = *(const int4*)(xbuf + (size_t)(m0 + sr) * 288 + k0 + sc);
#pragma unroll
    for (int gg = 0; gg < 3; ++gg)
      *(int4*)&Bs[gg][sr * 32 + sc] =
          *(const int4*)(wiht + (size_t)(gg * 1024 + n0 + sr) * 288 + k0 + sc);
    __syncthreads();
    short8 a = *(const short8*)&As[(wave * 16 + l15) * 32 + quad * 8];
#pragma unroll
    for (int gg = 0; gg < 3; ++gg) {
#pragma unroll
      for (int c = 0; c < 4; ++c) {
        short8 b = *(const short8*)&Bs[gg][(c * 16 + l15) * 32 + quad * 8];
        accv[gg][c] = __builtin_amdgcn_mfma_f32_16x16x32_bf16(a, b, accv[gg][c], 0, 0, 0);
      }
    }
    __syncthreads();
  }
#pragma unroll
  for (int c = 0; c < 4; ++c) {
#pragma unroll
    for (int r = 0; r < 4; ++r) {
      int b_idx = m0 + wave * 16 + quad * 4 + r;
      int j = n0 + c * 16 + l15;
      const float* g = G + (size_t)b_idx * 4096;
      float ir = accv[0][c][r] + bih[j];
      float iz = accv[1][c][r] + bih[1024 + j];
      float in_ = accv[2][c][r] + bih[2048 + j];
      float hr = g[1024 + j] + bhh[j];
      float hz = g[2048 + j] + bhh[1024 + j];
      float hn = g[3072 + j] + bhh[2048 + j];
      float rg = 1.f / (1.f + expf(-(ir + hr)));
      float u = 1.f / (1.f + expf(-(iz + hz)));
      float n = tanhf(in_ + rg * hn);
      float hprev = H[b_idx * 1024 + j];
      float hnext = (1.f - u) * n + u * hprev;
      featc[(size_t)(tt * NB + b_idx) * 1280 + j] = f2bf(hnext);
      float mask = 1.f - (float)dones[t * NB + b_idx];
      float hm = hnext * mask;
      H[b_idx * 1024 + j] = hm;
      HB[b_idx * 1024 + j] = f2bf(hm);
    }
  }
}

// ---------------------------------------------------------------------------
// Decoder-out GEMM + fused recon loss. A = DR1C bf16 cols 0:1024 (lda 2048),
// BT = DW2T [512][1024]. M=1792, N=512, K=1024. grid (8, 28).
// ---------------------------------------------------------------------------
__global__ __launch_bounds__(256) void decobs_loss_kernel(
    const ushort* __restrict__ A, const ushort* __restrict__ BT,
    const float* __restrict__ bias, const float* __restrict__ obs_next_g,
    float* __restrict__ acc) {
  __shared__ __align__(16) ushort As[64 * 32];
  __shared__ __align__(16) ushort Bs[64 * 32];
  int tid = threadIdx.x;
  int wave = tid >> 6, lane = tid & 63;
  int quad = lane >> 4, l15 = lane & 15;
  int m0 = blockIdx.y * 64, n0 = blockIdx.x * 64;
  int sr = tid >> 2, sc = (tid & 3) * 8;
  f32x4 accm[4] = {};
  for (int k0 = 0; k0 < 1024; k0 += 32) {
    *(int4*)&As[sr * 32 + sc] = *(const int4*)(A + (size_t)(m0 + sr) * 2048 + k0 + sc);
    *(int4*)&Bs[sr * 32 + sc] = *(const int4*)(BT + (size_t)(n0 + sr) * 1024 + k0 + sc);
    __syncthreads();
    short8 a = *(const short8*)&As[(wave * 16 + l15) * 32 + quad * 8];
#pragma unroll
    for (int c = 0; c < 4; ++c) {
      short8 b = *(const short8*)&Bs[(c * 16 + l15) * 32 + quad * 8];
      accm[c] = __builtin_amdgcn_mfma_f32_16x16x32_bf16(a, b, accm[c], 0, 0, 0);
    }
    __syncthreads();
  }
  float local = 0.f;
#pragma unroll
  for (int c = 0; c < 4; ++c) {
#pragma unroll
    for (int r = 0; r < 4; ++r) {
      size_t row = m0 + wave * 16 + quad * 4 + r;
      int col = n0 + c * 16 + l15;
      float v = accm[c][r] + bias[col];
      float d = v - obs_next_g[row * 512 + col];
      local += d * d;
    }
  }
  __shared__ float red[256];
  red[tid] = local;
  __syncthreads();
  for (int st = 128; st > 0; st >>= 1) {
    if (tid < st) red[tid] += red[tid + st];
    __syncthreads();
  }
  if (tid == 0) atomicAdd(&acc[0], red[0]);
}

// Reward matvec + loss. R1 = DR1C + 1024 (bf16, row stride 2048).
__global__ __launch_bounds__(256) void rew_loss_kernel(
    const ushort* __restrict__ R1, const float* __restrict__ w2,
    const float* __restrict__ b2, const float* __restrict__ rewards_g,
    float* __restrict__ acc) {
  int wave = threadIdx.x >> 6;
  int lane = threadIdx.x & 63;
  int row = blockIdx.x * 4 + wave;
  const ushort* rp = R1 + (size_t)row * 2048;
  float s = 0.f;
#pragma unroll
  for (int i = 0; i < 16; ++i) s += bf2f(rp[lane + 64 * i]) * w2[lane + 64 * i];
  for (int off = 32; off > 0; off >>= 1) s += __shfl_down(s, off);
  if (lane == 0) {
    float d = s + b2[0] - rewards_g[row];
    atomicAdd(&acc[1], d * d);
  }
}

__global__ void finalize_kernel(const float* __restrict__ acc, float* __restrict__ out) {
  float recon = acc[0] / ((float)NROWS * 512.f);
  float rew = acc[1] / (float)NROWS;
  float kl = acc[2] / (float)NROWS;
  out[0] = recon + rew + kl;
  out[1] = recon;
  out[2] = rew;
  out[3] = kl;
}

}  // namespace

extern "C" void kernel_launch(void* const* d_in, const int* in_sizes, int n_in,
                              void* d_out, int out_size, void* d_ws, size_t ws_size,
                              hipStream_t stream) {
  const float* obs     = (const float*)d_in[0];
  const float* actions = (const float*)d_in[1];
  const float* rewards = (const float*)d_in[2];
  const unsigned char* dones = (const unsigned char*)d_in[3];
  const float* eps     = (const float*)d_in[4];
  const float* enc_w1  = (const float*)d_in[5];
  const float* enc_b1  = (const float*)d_in[6];
  const float* enc_w2  = (const float*)d_in[7];
  const float* enc_b2  = (const float*)d_in[8];
  const float* gru_wih = (const float*)d_in[9];
  const float* gru_whh = (const float*)d_in[10];
  const float* gru_bih = (const float*)d_in[11];
  const float* gru_bhh = (const float*)d_in[12];
  const float* prior_w = (const float*)d_in[13];
  const float* prior_b = (const float*)d_in[14];
  const float* post_w  = (const float*)d_in[15];
  const float* post_b  = (const float*)d_in[16];
  const float* dec_w1  = (const float*)d_in[17];
  const float* dec_b1  = (const float*)d_in[18];
  const float* dec_w2  = (const float*)d_in[19];
  const float* dec_b2  = (const float*)d_in[20];
  const float* rew_w1  = (const float*)d_in[21];
  const float* rew_b1  = (const float*)d_in[22];
  const float* rew_w2  = (const float*)d_in[23];
  const float* rew_b2  = (const float*)d_in[24];
  float* out = (float*)d_out;
  float* ws = (float*)d_ws;

  float*  POSTE = ws + OFF_POSTE;
  ushort* OBSB  = (ushort*)(ws + OFF_OBSB);
  ushort* E1C   = (ushort*)(ws + OFF_E1C);
  ushort* EMBC  = (ushort*)(ws + OFF_EMBC);
  ushort* FEATC = (ushort*)(ws + OFF_FEATC);
  ushort* DR1C  = (ushort*)(ws + OFF_DR1C);
  ushort* WHT   = (ushort*)(ws + OFF_WHT);
  ushort* WIHT  = (ushort*)(ws + OFF_WIHT);
  ushort* WDRT  = (ushort*)(ws + OFF_WDRT);
  ushort* E1T   = (ushort*)(ws + OFF_E1T);
  ushort* E2T   = (ushort*)(ws + OFF_E2T);
  ushort* PET   = (ushort*)(ws + OFF_PET);
  ushort* DW2T  = (ushort*)(ws + OFF_DW2T);
  float*  BDR   = ws + OFF_BDR;
  float*  G     = ws + OFF_G;
  float*  H     = ws + OFF_H;
  ushort* HB    = (ushort*)(ws + OFF_HB);
  float*  ACC   = ws + OFF_ACC;
  ushort* XBUF  = (ushort*)(ws + OFF_XBUF);

  // Phase 0: zero H + HB + ACC (contiguous floats), build bf16 weights
  {
    int nzero = NB * 1024 + NB * 1024 / 2 + 16;  // H + HB + ACC
    zero_kernel<<<(nzero + 255) / 256, 256, 0, stream>>>(H, nzero);
  }
  build_wht<<<4096 * 1024 / 256, 256, 0, stream>>>(prior_w, post_w, gru_whh, WHT);
  f2bf_kernel<<<(3072 * 288) / 256, 256, 0, stream>>>(gru_wih, WIHT, 3072 * 288);
  trans_conv<<<dim3(1024 / 32, 1280 / 32), 256, 0, stream>>>(dec_w1, WDRT, 1024, 1280);
  trans_conv<<<dim3(1024 / 32, 1280 / 32), 256, 0, stream>>>(rew_w1, WDRT + (size_t)1024 * 1280, 1024, 1280);
  trans_conv<<<dim3(1024 / 32, 512 / 32), 256, 0, stream>>>(enc_w1, E1T, 1024, 512);
  trans_conv<<<dim3(1024 / 32, 1024 / 32), 256, 0, stream>>>(enc_w2, E2T, 1024, 1024);
  trans_conv<<<dim3(512 / 32, 1024 / 32), 256, 0, stream>>>(post_w + (size_t)1024 * 512, PET, 512, 1024);
  trans_conv<<<dim3(512 / 32, 1024 / 32), 256, 0, stream>>>(dec_w2, DW2T, 512, 1024);
  build_bdr<<<8, 256, 0, stream>>>(dec_b1, rew_b1, BDR);

  // Phase A: encoder + posterior-from-emb, chunked per group
  for (int g = 0; g < NGRP; ++g) {
    const float* obs_g = obs + (size_t)g * GROWS * 512;
    f2bf_kernel<<<(GROWS * 512) / 256, 256, 0, stream>>>(obs_g, OBSB, GROWS * 512);
    gemm_bf16<1><<<dim3(16, GROWS / 64), 256, 0, stream>>>(
        OBSB, E1T, enc_b1, E1C, 512, 512, 512, 1024);
    gemm_bf16<1><<<dim3(16, GROWS / 64), 256, 0, stream>>>(
        E1C, E2T, enc_b2, EMBC, 1024, 1024, 1024, 1024);
    gemm_bf16<2><<<dim3(8, GROWS / 64), 256, 0, stream>>>(
        EMBC, PET, post_b, POSTE + (size_t)g * GROWS * 512, 1024, 1024, 1024, 512);
  }

  // Phase B (sequential) interleaved with per-group head losses
  for (int g = 0; g < NGRP; ++g) {
    for (int tt = 0; tt < TGRP; ++tt) {
      int t = g * TGRP + tt;
      gemm_bf16<0><<<dim3(64, 4), 256, 0, stream>>>(
          HB, WHT, nullptr, G, 1024, 1024, 1024, 4096);
      step_latent_kernel<<<NB, 256, 0, stream>>>(t, tt, G, POSTE, prior_b, eps,
                                                 actions, XBUF, FEATC, ACC);
      gru_step_kernel<<<dim3(16, 4), 256, 0, stream>>>(t, tt, XBUF, WIHT, G, gru_bih,
                                                       gru_bhh, dones, H, HB, FEATC);
    }
    gemm_bf16<1><<<dim3(32, GROWS / 64), 256, 0, stream>>>(
        FEATC, WDRT, BDR, DR1C, 1280, 1280, 1280, 2048);
    decobs_loss_kernel<<<dim3(8, GROWS / 64), 256, 0, stream>>>(
        DR1C, DW2T, dec_b2, obs + ((size_t)g * TGRP + 1) * NB * 512, ACC);
    rew_loss_kernel<<<GROWS / 4, 256, 0, stream>>>(
        DR1C + 1024, rew_w2, rew_b2, rewards + (size_t)g * TGRP * NB, ACC);
  }

  finalize_kernel<<<1, 1, 0, stream>>>(ACC, out);
}

// Round 5
// 3135.210 us; speedup vs baseline: 3.0580x; 1.1417x over previous
//
#include <hip/hip_runtime.h>
#include <math.h>

// ---------------------------------------------------------------------------
// WorldModel RSSM forward losses — R5.
// R4 passed at 3579us. This round attacks the sequential Phase B:
//  1) latent/KL math fused into the h@WHT GEMM epilogue via a column
//     permutation of WHT (cols [pm|pl|qm|ql] interleaved per 16-s group) so
//     each wave's 4 acc tiles are exactly the 4 latent quantities.
//  2) register-prefetch double buffering (BK=64) in the step GEMM; prefetch
//     in the GRU GEMM — we run at 1 wave/SIMD so ILP is the only latency hiding.
//  3) LDS stride padding (32->40, 64->72 ushorts) to kill 8/16-way bank
//     conflicts on ds_read_b128 fragment loads (m136: 2-way is free).
// ---------------------------------------------------------------------------

namespace {

typedef unsigned short ushort;
typedef __attribute__((ext_vector_type(8))) short short8;   // 8 bf16 in 4 VGPRs
typedef __attribute__((ext_vector_type(4))) float f32x4;

constexpr int TSTEPS = 63;
constexpr int NB     = 256;
constexpr int NACT   = 32;
constexpr int NROWS  = TSTEPS * NB;   // 16128
constexpr int TGRP   = 7;
constexpr int NGRP   = 9;
constexpr int GROWS  = TGRP * NB;     // 1792 = 28*64

// ---- workspace layout (floats) --------------------------------------------
constexpr size_t OFF_POSTE = 0;                                     // f32 16128x512
constexpr size_t OFF_OBSB  = OFF_POSTE + (size_t)NROWS * 512;       // u16 1792x512
constexpr size_t OFF_E1C   = OFF_OBSB + (size_t)GROWS * 512 / 2;    // u16 1792x1024
constexpr size_t OFF_EMBC  = OFF_E1C + (size_t)GROWS * 1024 / 2;    // u16 1792x1024
constexpr size_t OFF_FEATC = OFF_EMBC + (size_t)GROWS * 1024 / 2;   // u16 1792x1280
constexpr size_t OFF_DR1C  = OFF_FEATC + (size_t)GROWS * 1280 / 2;  // u16 1792x2048
constexpr size_t OFF_WHT   = OFF_DR1C + (size_t)GROWS * 2048 / 2;   // u16 4096x1024
constexpr size_t OFF_WIHT  = OFF_WHT + (size_t)4096 * 1024 / 2;     // u16 3072x288
constexpr size_t OFF_WDRT  = OFF_WIHT + (size_t)3072 * 288 / 2;     // u16 2048x1280
constexpr size_t OFF_E1T   = OFF_WDRT + (size_t)2048 * 1280 / 2;    // u16 1024x512
constexpr size_t OFF_E2T   = OFF_E1T + (size_t)1024 * 512 / 2;      // u16 1024x1024
constexpr size_t OFF_PET   = OFF_E2T + (size_t)1024 * 1024 / 2;     // u16 512x1024
constexpr size_t OFF_DW2T  = OFF_PET + (size_t)512 * 1024 / 2;      // u16 512x1024
constexpr size_t OFF_BDR   = OFF_DW2T + (size_t)512 * 1024 / 2;     // f32 2048
constexpr size_t OFF_G     = OFF_BDR + 2048;                        // f32 256x3072
constexpr size_t OFF_H     = OFF_G + (size_t)NB * 3072;             // f32 256x1024
constexpr size_t OFF_HB    = OFF_H + (size_t)NB * 1024;             // u16 256x1024
constexpr size_t OFF_ACC   = OFF_HB + (size_t)NB * 1024 / 2;        // f32 16
constexpr size_t OFF_XBUF  = OFF_ACC + 16;                          // u16 256x288

__device__ __forceinline__ ushort f2bf(float f) {
  unsigned int u = __float_as_uint(f);
  unsigned int r = (u + 0x7fffu + ((u >> 16) & 1u)) >> 16;
  return (ushort)r;
}
__device__ __forceinline__ float bf2f(ushort u) {
  return __uint_as_float((unsigned int)u << 16);
}

__global__ void zero_kernel(float* p, int n) {
  int i = blockIdx.x * 256 + threadIdx.x;
  if (i < n) p[i] = 0.f;
}

__global__ void f2bf_kernel(const float* __restrict__ in, ushort* __restrict__ out, int n) {
  int i = blockIdx.x * 256 + threadIdx.x;
  if (i < n) out[i] = f2bf(in[i]);
}

// WHT[n][k]. n<1024: latent-permuted — group g=n>>6 covers s=g*16..g*16+15,
// quad q=(n>>4)&3 selects pm/pl/qm/ql, s = (n>>6)*16 + (n&15).
// n>=1024: whh[n-1024][k] (gh part).
__global__ void build_wht(const float* __restrict__ prior_w, const float* __restrict__ post_w,
                          const float* __restrict__ whh, ushort* __restrict__ out) {
  int idx = blockIdx.x * 256 + threadIdx.x;  // 4096*1024
  int n = idx >> 10, k = idx & 1023;
  float v;
  if (n < 1024) {
    int q = (n >> 4) & 3;
    int s = ((n >> 6) << 4) | (n & 15);
    v = (q == 0) ? prior_w[k * 512 + s]
      : (q == 1) ? prior_w[k * 512 + 256 + s]
      : (q == 2) ? post_w[k * 512 + s]
                 : post_w[k * 512 + 256 + s];
  } else {
    v = whh[(size_t)(n - 1024) * 1024 + k];
  }
  out[idx] = f2bf(v);
}

// out[c*ldo + r] = bf16(in[r*ldi + c]); grid (C/32, R/32)
__global__ void trans_conv(const float* __restrict__ in, ushort* __restrict__ out,
                           int ldi, int ldo) {
  __shared__ float tile[32][33];
  int r0 = blockIdx.y * 32, c0 = blockIdx.x * 32;
  int tx = threadIdx.x & 31, ty = threadIdx.x >> 5;
#pragma unroll
  for (int p = 0; p < 4; ++p)
    tile[ty + p * 8][tx] = in[(size_t)(r0 + ty + p * 8) * ldi + c0 + tx];
  __syncthreads();
#pragma unroll
  for (int p = 0; p < 4; ++p)
    out[(size_t)(c0 + ty + p * 8) * ldo + r0 + tx] = f2bf(tile[tx][ty + p * 8]);
}

__global__ void build_bdr(const float* __restrict__ dec_b1, const float* __restrict__ rew_b1,
                          float* __restrict__ bdr) {
  int i = blockIdx.x * 256 + threadIdx.x;  // 2048
  bdr[i] = (i < 1024) ? dec_b1[i] : rew_b1[i - 1024];
}

// ---------------------------------------------------------------------------
// Phase A/C bf16 GEMM: C[M,N] = A @ B; A bf16 [M][K], BT bf16 [N][K].
// 64x64 tile, 4 waves, BK=32, LDS stride 40 (2-way-free bank pattern).
// EPI: 1 = +bias, relu, store bf16; 2 = +bias, store f32.
// ---------------------------------------------------------------------------
template <int EPI>
__global__ __launch_bounds__(256) void gemm_bf16(
    const ushort* __restrict__ A, const ushort* __restrict__ BT,
    const float* __restrict__ bias, void* __restrict__ Cv,
    int K, int lda, int ldb, int ldc) {
  __shared__ __align__(16) ushort As[64 * 40];
  __shared__ __align__(16) ushort Bs[64 * 40];
  int tid = threadIdx.x;
  int wave = tid >> 6, lane = tid & 63;
  int quad = lane >> 4, l15 = lane & 15;
  int m0 = blockIdx.y * 64, n0 = blockIdx.x * 64;
  int sr = tid >> 2, sc = (tid & 3) * 8;
  f32x4 acc[4] = {};
  for (int k0 = 0; k0 < K; k0 += 32) {
    *(int4*)&As[sr * 40 + sc] = *(const int4*)(A + (size_t)(m0 + sr) * lda + k0 + sc);
    *(int4*)&Bs[sr * 40 + sc] = *(const int4*)(BT + (size_t)(n0 + sr) * ldb + k0 + sc);
    __syncthreads();
    short8 a = *(const short8*)&As[(wave * 16 + l15) * 40 + quad * 8];
#pragma unroll
    for (int c = 0; c < 4; ++c) {
      short8 b = *(const short8*)&Bs[(c * 16 + l15) * 40 + quad * 8];
      acc[c] = __builtin_amdgcn_mfma_f32_16x16x32_bf16(a, b, acc[c], 0, 0, 0);
    }
    __syncthreads();
  }
#pragma unroll
  for (int c = 0; c < 4; ++c) {
#pragma unroll
    for (int r = 0; r < 4; ++r) {
      size_t row = m0 + wave * 16 + quad * 4 + r;
      int col = n0 + c * 16 + l15;
      float v = acc[c][r] + bias[col];
      if (EPI == 1) v = fmaxf(v, 0.f);
      if (EPI == 1) ((ushort*)Cv)[row * ldc + col] = f2bf(v);
      else ((float*)Cv)[row * ldc + col] = v;
    }
  }
}

// ---------------------------------------------------------------------------
// Phase B kernel 1: G = HB @ WHT (M=256, N=4096, K=1024), BK=64, register
// prefetch. Blocks with blockIdx.x<16 own the latent-permuted columns: their
// 4 acc tiles = (pm,pl,qm,ql) for s=blockIdx.x*16+l15 — fused z/KL epilogue.
// Other blocks store gh (cols n0-1024) to G [256][3072] f32.
// ---------------------------------------------------------------------------
__global__ __launch_bounds__(256) void step_g_kernel(
    int t, int tt, const ushort* __restrict__ HB, const ushort* __restrict__ WHT,
    const float* __restrict__ prior_b, const float* __restrict__ poste,
    const float* __restrict__ eps, const float* __restrict__ actions,
    float* __restrict__ G, ushort* __restrict__ xbuf,
    ushort* __restrict__ featc, float* __restrict__ acc_kl) {
  __shared__ __align__(16) ushort As[64 * 72];
  __shared__ __align__(16) ushort Bs[64 * 72];
  int tid = threadIdx.x;
  int wave = tid >> 6, lane = tid & 63;
  int quad = lane >> 4, l15 = lane & 15;
  int m0 = blockIdx.y * 64, n0 = blockIdx.x * 64;
  int sr = tid >> 2, sc = (tid & 3) * 16;
  const ushort* agp = HB + (size_t)(m0 + sr) * 1024 + sc;
  const ushort* bgp = WHT + (size_t)(n0 + sr) * 1024 + sc;
  int4 a0 = *(const int4*)agp, a1 = *(const int4*)(agp + 8);
  int4 b0 = *(const int4*)bgp, b1 = *(const int4*)(bgp + 8);
  f32x4 acc[4] = {};
  for (int k0 = 0;;) {
    *(int4*)&As[sr * 72 + sc] = a0; *(int4*)&As[sr * 72 + sc + 8] = a1;
    *(int4*)&Bs[sr * 72 + sc] = b0; *(int4*)&Bs[sr * 72 + sc + 8] = b1;
    __syncthreads();
    int kn = k0 + 64;
    if (kn < 1024) {
      a0 = *(const int4*)(agp + kn); a1 = *(const int4*)(agp + kn + 8);
      b0 = *(const int4*)(bgp + kn); b1 = *(const int4*)(bgp + kn + 8);
    }
#pragma unroll
    for (int kk = 0; kk < 2; ++kk) {
      short8 a = *(const short8*)&As[(wave * 16 + l15) * 72 + kk * 32 + quad * 8];
#pragma unroll
      for (int c = 0; c < 4; ++c) {
        short8 b = *(const short8*)&Bs[(c * 16 + l15) * 72 + kk * 32 + quad * 8];
        acc[c] = __builtin_amdgcn_mfma_f32_16x16x32_bf16(a, b, acc[c], 0, 0, 0);
      }
    }
    k0 = kn;
    if (k0 >= 1024) break;
    __syncthreads();
  }
  if (blockIdx.x < 16) {
    // latent epilogue: acc[0..3] = pm,pl,qm,ql for s = blockIdx.x*16 + l15
    int s = (n0 >> 2) + l15;
    float kl_sum = 0.f;
#pragma unroll
    for (int r = 0; r < 4; ++r) {
      int b = m0 + wave * 16 + quad * 4 + r;
      size_t row = (size_t)t * NB + b;
      float pm = acc[0][r] + prior_b[s];
      float pl = acc[1][r] + prior_b[256 + s];
      float qm = acc[2][r] + poste[row * 512 + s];
      float ql = acc[3][r] + poste[row * 512 + 256 + s];
      float e = eps[row * 256 + s];
      float z = qm + e * expf(ql);
      xbuf[b * 288 + s] = f2bf(z);
      featc[(size_t)(tt * NB + b) * 1280 + 1024 + s] = f2bf(z);
      if (s < NACT) xbuf[b * 288 + 256 + s] = f2bf(actions[row * NACT + s]);
      float vq = expf(2.f * ql), vp = expf(2.f * pl);
      float dm = qm - pm;
      kl_sum += pl - ql + (vq + dm * dm) / (vp + 1e-8f) - 1.f;
    }
    for (int off = 32; off > 0; off >>= 1) kl_sum += __shfl_down(kl_sum, off);
    if (lane == 0) atomicAdd(acc_kl, 0.5f * kl_sum);
  } else {
    int ng = n0 - 1024;
#pragma unroll
    for (int c = 0; c < 4; ++c)
#pragma unroll
      for (int r = 0; r < 4; ++r) {
        int b = m0 + wave * 16 + quad * 4 + r;
        G[(size_t)b * 3072 + ng + c * 16 + l15] = acc[c][r];
      }
  }
}

// ---------------------------------------------------------------------------
// Phase B kernel 2: GI = xbuf @ wih^T (3 gates), fused GRU gate epilogue.
// grid (16,4), BK=32, register prefetch, padded LDS.
// ---------------------------------------------------------------------------
__global__ __launch_bounds__(256) void gru_step_kernel(
    int t, int tt, const ushort* __restrict__ xbuf, const ushort* __restrict__ wiht,
    const float* __restrict__ G, const float* __restrict__ bih,
    const float* __restrict__ bhh, const unsigned char* __restrict__ dones,
    float* __restrict__ H, ushort* __restrict__ HB, ushort* __restrict__ featc) {
  __shared__ __align__(16) ushort As[64 * 40];
  __shared__ __align__(16) ushort Bs[3][64 * 40];
  int tid = threadIdx.x;
  int wave = tid >> 6, lane = tid & 63;
  int quad = lane >> 4, l15 = lane & 15;
  int m0 = blockIdx.y * 64, n0 = blockIdx.x * 64;
  int sr = tid >> 2, sc = (tid & 3) * 8;
  const ushort* agp = xbuf + (size_t)(m0 + sr) * 288 + sc;
  const ushort* bgp0 = wiht + (size_t)(n0 + sr) * 288 + sc;
  int4 pa = *(const int4*)agp;
  int4 pb0 = *(const int4*)bgp0;
  int4 pb1 = *(const int4*)(bgp0 + (size_t)1024 * 288);
  int4 pb2 = *(const int4*)(bgp0 + (size_t)2048 * 288);
  f32x4 accv[3][4] = {};
  for (int k0 = 0;;) {
    *(int4*)&As[sr * 40 + sc] = pa;
    *(int4*)&Bs[0][sr * 40 + sc] = pb0;
    *(int4*)&Bs[1][sr * 40 + sc] = pb1;
    *(int4*)&Bs[2][sr * 40 + sc] = pb2;
    __syncthreads();
    int kn = k0 + 32;
    if (kn < 288) {
      pa = *(const int4*)(agp + kn);
      pb0 = *(const int4*)(bgp0 + kn);
      pb1 = *(const int4*)(bgp0 + (size_t)1024 * 288 + kn);
      pb2 = *(const int4*)(bgp0 + (size_t)2048 * 288 + kn);
    }
    short8 a = *(const short8*)&As[(wave * 16 + l15) * 40 + quad * 8];
#pragma unroll
    for (int gg = 0; gg < 3; ++gg) {
#pragma unroll
      for (int c = 0; c < 4; ++c) {
        short8 b = *(const short8*)&Bs[gg][(c * 16 + l15) * 40 + quad * 8];
        accv[gg][c] = __builtin_amdgcn_mfma_f32_16x16x32_bf16(a, b, accv[gg][c], 0, 0, 0);
      }
    }
    k0 = kn;
    if (k0 >= 288) break;
    __syncthreads();
  }
#pragma unroll
  for (int c = 0; c < 4; ++c) {
#pragma unroll
    for (int r = 0; r < 4; ++r) {
      int b_idx = m0 + wave * 16 + quad * 4 + r;
      int j = n0 + c * 16 + l15;
      const float* g = G + (size_t)b_idx * 3072;
      float ir = accv[0][c][r] + bih[j];
      float iz = accv[1][c][r] + bih[1024 + j];
      float in_ = accv[2][c][r] + bih[2048 + j];
      float hr = g[j] + bhh[j];
      float hz = g[1024 + j] + bhh[1024 + j];
      float hn = g[2048 + j] + bhh[2048 + j];
      float rg = 1.f / (1.f + expf(-(ir + hr)));
      float u = 1.f / (1.f + expf(-(iz + hz)));
      float n = tanhf(in_ + rg * hn);
      float hprev = H[b_idx * 1024 + j];
      float hnext = (1.f - u) * n + u * hprev;
      featc[(size_t)(tt * NB + b_idx) * 1280 + j] = f2bf(hnext);
      float mask = 1.f - (float)dones[t * NB + b_idx];
      float hm = hnext * mask;
      H[b_idx * 1024 + j] = hm;
      HB[b_idx * 1024 + j] = f2bf(hm);
    }
  }
}

// ---------------------------------------------------------------------------
// Decoder-out GEMM + fused recon loss. A = DR1C bf16 cols 0:1024 (lda 2048),
// BT = DW2T [512][1024]. M=1792, N=512, K=1024. grid (8, 28).
// ---------------------------------------------------------------------------
__global__ __launch_bounds__(256) void decobs_loss_kernel(
    const ushort* __restrict__ A, const ushort* __restrict__ BT,
    const float* __restrict__ bias, const float* __restrict__ obs_next_g,
    float* __restrict__ acc) {
  __shared__ __align__(16) ushort As[64 * 40];
  __shared__ __align__(16) ushort Bs[64 * 40];
  int tid = threadIdx.x;
  int wave = tid >> 6, lane = tid & 63;
  int quad = lane >> 4, l15 = lane & 15;
  int m0 = blockIdx.y * 64, n0 = blockIdx.x * 64;
  int sr = tid >> 2, sc = (tid & 3) * 8;
  f32x4 accm[4] = {};
  for (int k0 = 0; k0 < 1024; k0 += 32) {
    *(int4*)&As[sr * 40 + sc] = *(const int4*)(A + (size_t)(m0 + sr) * 2048 + k0 + sc);
    *(int4*)&Bs[sr * 40 + sc] = *(const int4*)(BT + (size_t)(n0 + sr) * 1024 + k0 + sc);
    __syncthreads();
    short8 a = *(const short8*)&As[(wave * 16 + l15) * 40 + quad * 8];
#pragma unroll
    for (int c = 0; c < 4; ++c) {
      short8 b = *(const short8*)&Bs[(c * 16 + l15) * 40 + quad * 8];
      accm[c] = __builtin_amdgcn_mfma_f32_16x16x32_bf16(a, b, accm[c], 0, 0, 0);
    }
    __syncthreads();
  }
  float local = 0.f;
#pragma unroll
  for (int c = 0; c < 4; ++c) {
#pragma unroll
    for (int r = 0; r < 4; ++r) {
      size_t row = m0 + wave * 16 + quad * 4 + r;
      int col = n0 + c * 16 + l15;
      float v = accm[c][r] + bias[col];
      float d = v - obs_next_g[row * 512 + col];
      local += d * d;
    }
  }
  __shared__ float red[256];
  red[tid] = local;
  __syncthreads();
  for (int st = 128; st > 0; st >>= 1) {
    if (tid < st) red[tid] += red[tid + st];
    __syncthreads();
  }
  if (tid == 0) atomicAdd(&acc[0], red[0]);
}

// Reward matvec + loss. R1 = DR1C + 1024 (bf16, row stride 2048).
__global__ __launch_bounds__(256) void rew_loss_kernel(
    const ushort* __restrict__ R1, const float* __restrict__ w2,
    const float* __restrict__ b2, const float* __restrict__ rewards_g,
    float* __restrict__ acc) {
  int wave = threadIdx.x >> 6;
  int lane = threadIdx.x & 63;
  int row = blockIdx.x * 4 + wave;
  const ushort* rp = R1 + (size_t)row * 2048;
  float s = 0.f;
#pragma unroll
  for (int i = 0; i < 16; ++i) s += bf2f(rp[lane + 64 * i]) * w2[lane + 64 * i];
  for (int off = 32; off > 0; off >>= 1) s += __shfl_down(s, off);
  if (lane == 0) {
    float d = s + b2[0] - rewards_g[row];
    atomicAdd(&acc[1], d * d);
  }
}

__global__ void finalize_kernel(const float* __restrict__ acc, float* __restrict__ out) {
  float recon = acc[0] / ((float)NROWS * 512.f);
  float rew = acc[1] / (float)NROWS;
  float kl = acc[2] / (float)NROWS;
  out[0] = recon + rew + kl;
  out[1] = recon;
  out[2] = rew;
  out[3] = kl;
}

}  // namespace

extern "C" void kernel_launch(void* const* d_in, const int* in_sizes, int n_in,
                              void* d_out, int out_size, void* d_ws, size_t ws_size,
                              hipStream_t stream) {
  const float* obs     = (const float*)d_in[0];
  const float* actions = (const float*)d_in[1];
  const float* rewards = (const float*)d_in[2];
  const unsigned char* dones = (const unsigned char*)d_in[3];
  const float* eps     = (const float*)d_in[4];
  const float* enc_w1  = (const float*)d_in[5];
  const float* enc_b1  = (const float*)d_in[6];
  const float* enc_w2  = (const float*)d_in[7];
  const float* enc_b2  = (const float*)d_in[8];
  const float* gru_wih = (const float*)d_in[9];
  const float* gru_whh = (const float*)d_in[10];
  const float* gru_bih = (const float*)d_in[11];
  const float* gru_bhh = (const float*)d_in[12];
  const float* prior_w = (const float*)d_in[13];
  const float* prior_b = (const float*)d_in[14];
  const float* post_w  = (const float*)d_in[15];
  const float* post_b  = (const float*)d_in[16];
  const float* dec_w1  = (const float*)d_in[17];
  const float* dec_b1  = (const float*)d_in[18];
  const float* dec_w2  = (const float*)d_in[19];
  const float* dec_b2  = (const float*)d_in[20];
  const float* rew_w1  = (const float*)d_in[21];
  const float* rew_b1  = (const float*)d_in[22];
  const float* rew_w2  = (const float*)d_in[23];
  const float* rew_b2  = (const float*)d_in[24];
  float* out = (float*)d_out;
  float* ws = (float*)d_ws;

  float*  POSTE = ws + OFF_POSTE;
  ushort* OBSB  = (ushort*)(ws + OFF_OBSB);
  ushort* E1C   = (ushort*)(ws + OFF_E1C);
  ushort* EMBC  = (ushort*)(ws + OFF_EMBC);
  ushort* FEATC = (ushort*)(ws + OFF_FEATC);
  ushort* DR1C  = (ushort*)(ws + OFF_DR1C);
  ushort* WHT   = (ushort*)(ws + OFF_WHT);
  ushort* WIHT  = (ushort*)(ws + OFF_WIHT);
  ushort* WDRT  = (ushort*)(ws + OFF_WDRT);
  ushort* E1T   = (ushort*)(ws + OFF_E1T);
  ushort* E2T   = (ushort*)(ws + OFF_E2T);
  ushort* PET   = (ushort*)(ws + OFF_PET);
  ushort* DW2T  = (ushort*)(ws + OFF_DW2T);
  float*  BDR   = ws + OFF_BDR;
  float*  G     = ws + OFF_G;
  float*  H     = ws + OFF_H;
  ushort* HB    = (ushort*)(ws + OFF_HB);
  float*  ACC   = ws + OFF_ACC;
  ushort* XBUF  = (ushort*)(ws + OFF_XBUF);

  // Phase 0: zero H + HB + ACC (contiguous), build bf16 weights
  {
    int nzero = NB * 1024 + NB * 512 + 16;  // H + HB + ACC
    zero_kernel<<<(nzero + 255) / 256, 256, 0, stream>>>(H, nzero);
  }
  build_wht<<<4096 * 1024 / 256, 256, 0, stream>>>(prior_w, post_w, gru_whh, WHT);
  f2bf_kernel<<<(3072 * 288) / 256, 256, 0, stream>>>(gru_wih, WIHT, 3072 * 288);
  trans_conv<<<dim3(1024 / 32, 1280 / 32), 256, 0, stream>>>(dec_w1, WDRT, 1024, 1280);
  trans_conv<<<dim3(1024 / 32, 1280 / 32), 256, 0, stream>>>(rew_w1, WDRT + (size_t)1024 * 1280, 1024, 1280);
  trans_conv<<<dim3(1024 / 32, 512 / 32), 256, 0, stream>>>(enc_w1, E1T, 1024, 512);
  trans_conv<<<dim3(1024 / 32, 1024 / 32), 256, 0, stream>>>(enc_w2, E2T, 1024, 1024);
  trans_conv<<<dim3(512 / 32, 1024 / 32), 256, 0, stream>>>(post_w + (size_t)1024 * 512, PET, 512, 1024);
  trans_conv<<<dim3(512 / 32, 1024 / 32), 256, 0, stream>>>(dec_w2, DW2T, 512, 1024);
  build_bdr<<<8, 256, 0, stream>>>(dec_b1, rew_b1, BDR);

  // Phase A: encoder + posterior-from-emb, chunked per group
  for (int g = 0; g < NGRP; ++g) {
    const float* obs_g = obs + (size_t)g * GROWS * 512;
    f2bf_kernel<<<(GROWS * 512) / 256, 256, 0, stream>>>(obs_g, OBSB, GROWS * 512);
    gemm_bf16<1><<<dim3(16, GROWS / 64), 256, 0, stream>>>(
        OBSB, E1T, enc_b1, E1C, 512, 512, 512, 1024);
    gemm_bf16<1><<<dim3(16, GROWS / 64), 256, 0, stream>>>(
        E1C, E2T, enc_b2, EMBC, 1024, 1024, 1024, 1024);
    gemm_bf16<2><<<dim3(8, GROWS / 64), 256, 0, stream>>>(
        EMBC, PET, post_b, POSTE + (size_t)g * GROWS * 512, 1024, 1024, 1024, 512);
  }

  // Phase B (sequential, 2 kernels/step) interleaved with per-group heads
  for (int g = 0; g < NGRP; ++g) {
    for (int tt = 0; tt < TGRP; ++tt) {
      int t = g * TGRP + tt;
      step_g_kernel<<<dim3(64, 4), 256, 0, stream>>>(
          t, tt, HB, WHT, prior_b, POSTE, eps, actions, G, XBUF, FEATC, &ACC[2]);
      gru_step_kernel<<<dim3(16, 4), 256, 0, stream>>>(
          t, tt, XBUF, WIHT, G, gru_bih, gru_bhh, dones, H, HB, FEATC);
    }
    gemm_bf16<1><<<dim3(32, GROWS / 64), 256, 0, stream>>>(
        FEATC, WDRT, BDR, DR1C, 1280, 1280, 1280, 2048);
    decobs_loss_kernel<<<dim3(8, GROWS / 64), 256, 0, stream>>>(
        DR1C, DW2T, dec_b2, obs + ((size_t)g * TGRP + 1) * NB * 512, ACC);
    rew_loss_kernel<<<GROWS / 4, 256, 0, stream>>>(
        DR1C + 1024, rew_w2, rew_b2, rewards + (size_t)g * TGRP * NB, ACC);
  }

  finalize_kernel<<<1, 1, 0, stream>>>(ACC, out);
}